// Round 1
// baseline (728.369 us; speedup 1.0000x reference)
//
#include <hip/hip_runtime.h>

// Reference collapses:
//   softmax over size-1 axis == 1  =>  res == v  (W1, W2 unused)
//   reshape (B,1,200)->(10,B,1,20)->(B,1,200) is identity on the flat buffer
//   => out = relu(x @ (gamma*W3 + W4)^T), x:(B,20), M:(200,20)
//
// Memory-bound: 210 MB out write + 21 MB x read => ~37 us floor @ 6.3 TB/s.

#define BATCH   262144
#define DICT    20
#define NCOLS   200                      // NUM_HEADS * DICT
#define NF4     (BATCH * (NCOLS / 4))    // 13,107,200 float4 outputs
#define NBLOCKS 3200
#define NTHREADS 256
// grid stride = 3200*256 = 819200, divisible by 50 => each thread's column
// group (j4) is invariant across the grid-stride loop, so the fused weight
// block stays resident in registers.

__global__ __launch_bounds__(NTHREADS, 4)
void attn_collapsed_kernel(const float* __restrict__ x,
                           const float* __restrict__ W3,
                           const float* __restrict__ W4,
                           const float* __restrict__ gamma,
                           float* __restrict__ out)
{
    const int tid = blockIdx.x * NTHREADS + threadIdx.x;
    const int j4  = tid % 50;            // this thread's 4 output columns
    const float g = gamma[0];

    // Prologue: fuse M[j][d] = g*W3[j][d] + W4[j][d] for j = 4*j4 .. 4*j4+3.
    // 80 floats -> registers (W3/W4 are 16 KB each, fully L1-resident).
    float m[4][DICT];
#pragma unroll
    for (int c = 0; c < 4; ++c) {
        const float4* w3 = (const float4*)(W3 + (4 * j4 + c) * DICT);
        const float4* w4 = (const float4*)(W4 + (4 * j4 + c) * DICT);
#pragma unroll
        for (int dd = 0; dd < 5; ++dd) {
            float4 a = w3[dd];
            float4 b = w4[dd];
            m[c][4 * dd + 0] = fmaf(g, a.x, b.x);
            m[c][4 * dd + 1] = fmaf(g, a.y, b.y);
            m[c][4 * dd + 2] = fmaf(g, a.z, b.z);
            m[c][4 * dd + 3] = fmaf(g, a.w, b.w);
        }
    }

    const int stride = NBLOCKS * NTHREADS;      // 819200 % 50 == 0
    for (int f = tid; f < NF4; f += stride) {
        const int r = f / 50;                    // batch row
        const float4* xr = (const float4*)(x + r * DICT);

        float xv[DICT];
#pragma unroll
        for (int dd = 0; dd < 5; ++dd) {
            float4 xx = xr[dd];
            xv[4 * dd + 0] = xx.x;
            xv[4 * dd + 1] = xx.y;
            xv[4 * dd + 2] = xx.z;
            xv[4 * dd + 3] = xx.w;
        }

        float4 acc;
        acc.x = 0.f; acc.y = 0.f; acc.z = 0.f; acc.w = 0.f;
#pragma unroll
        for (int d = 0; d < DICT; ++d) {
            const float xd = xv[d];
            acc.x = fmaf(xd, m[0][d], acc.x);
            acc.y = fmaf(xd, m[1][d], acc.y);
            acc.z = fmaf(xd, m[2][d], acc.z);
            acc.w = fmaf(xd, m[3][d], acc.w);
        }

        acc.x = fmaxf(acc.x, 0.f);
        acc.y = fmaxf(acc.y, 0.f);
        acc.z = fmaxf(acc.z, 0.f);
        acc.w = fmaxf(acc.w, 0.f);

        ((float4*)out)[f] = acc;   // lanes consecutive -> 1 KB coalesced store
    }
}

extern "C" void kernel_launch(void* const* d_in, const int* in_sizes, int n_in,
                              void* d_out, int out_size, void* d_ws, size_t ws_size,
                              hipStream_t stream) {
    const float* x     = (const float*)d_in[0];
    // d_in[1] = W1, d_in[2] = W2 : mathematically unused (softmax over size-1 axis)
    const float* W3    = (const float*)d_in[3];
    const float* W4    = (const float*)d_in[4];
    const float* gamma = (const float*)d_in[5];
    float* out = (float*)d_out;

    attn_collapsed_kernel<<<NBLOCKS, NTHREADS, 0, stream>>>(x, W3, W4, gamma, out);
}

// Round 2
// 324.529 us; speedup vs baseline: 2.2444x; 2.2444x over previous
//
#include <hip/hip_runtime.h>

// Reference collapses:
//   softmax over size-1 axis == 1  =>  att == 1  =>  res == v  (W1, W2 unused;
//   the (B,1,200)->(10,B,1,20) reshape is inverted by res.reshape(B,1,200))
//   => out = relu(x @ (gamma*W3 + W4)^T),  x:(B,20), fused M:(200,20)
//
// Memory-bound: 210 MB out write + 21 MB x read => ~37 us floor @ 6.3 TB/s.
//
// R1 lesson: 4 cols/thread (80-reg weight block) spilled at VGPR=64 ->
// 1.25 GB scratch fetch, 556 us. Now 2 cols/thread: ~60 VGPRs, no spill.

#define BATCH    262144
#define DICT     20
#define COLS     200                     // NUM_HEADS * DICT
#define NF2      (BATCH * (COLS / 2))    // 26,214,400 float2 outputs
#define NBLOCKS  3200
#define NTHREADS 256
// grid stride = 3200*256 = 819200; 819200 % 100 == 0 => each thread's column
// pair (j2) is invariant across the grid-stride loop, so the fused weight
// rows stay resident in registers.

__global__ __launch_bounds__(NTHREADS)
void attn_collapsed_kernel(const float* __restrict__ x,
                           const float* __restrict__ W3,
                           const float* __restrict__ W4,
                           const float* __restrict__ gamma,
                           float* __restrict__ out)
{
    const int tid = blockIdx.x * NTHREADS + threadIdx.x;
    const int j2  = tid % 100;           // owns output columns 2*j2, 2*j2+1
    const float g = gamma[0];

    // Fuse M[j][:] = g*W3[j][:] + W4[j][:] for the 2 owned columns.
    // Held as scalarized float4s (40 VGPRs) -> no spill.
    float4 m0[5], m1[5];
    {
        const float4* w3a = (const float4*)(W3 + (2 * j2 + 0) * DICT);
        const float4* w4a = (const float4*)(W4 + (2 * j2 + 0) * DICT);
        const float4* w3b = (const float4*)(W3 + (2 * j2 + 1) * DICT);
        const float4* w4b = (const float4*)(W4 + (2 * j2 + 1) * DICT);
#pragma unroll
        for (int i = 0; i < 5; ++i) {
            float4 a = w3a[i], b = w4a[i];
            m0[i].x = fmaf(g, a.x, b.x);
            m0[i].y = fmaf(g, a.y, b.y);
            m0[i].z = fmaf(g, a.z, b.z);
            m0[i].w = fmaf(g, a.w, b.w);
            a = w3b[i]; b = w4b[i];
            m1[i].x = fmaf(g, a.x, b.x);
            m1[i].y = fmaf(g, a.y, b.y);
            m1[i].z = fmaf(g, a.z, b.z);
            m1[i].w = fmaf(g, a.w, b.w);
        }
    }

    const int stride = NBLOCKS * NTHREADS;   // 819200, % 100 == 0
    for (int f = tid; f < NF2; f += stride) {
        const int r = f / 100;               // batch row
        const float4* xr = (const float4*)(x + r * DICT);

        float ax = 0.f, ay = 0.f;
#pragma unroll
        for (int i = 0; i < 5; ++i) {
            float4 xx = xr[i];               // L1-broadcast within the wave
            ax = fmaf(xx.x, m0[i].x, ax);
            ax = fmaf(xx.y, m0[i].y, ax);
            ax = fmaf(xx.z, m0[i].z, ax);
            ax = fmaf(xx.w, m0[i].w, ax);
            ay = fmaf(xx.x, m1[i].x, ay);
            ay = fmaf(xx.y, m1[i].y, ay);
            ay = fmaf(xx.z, m1[i].z, ay);
            ay = fmaf(xx.w, m1[i].w, ay);
        }

        float2 acc;
        acc.x = fmaxf(ax, 0.f);
        acc.y = fmaxf(ay, 0.f);
        ((float2*)out)[f] = acc;   // lanes consecutive -> 512 B coalesced store
    }
}

extern "C" void kernel_launch(void* const* d_in, const int* in_sizes, int n_in,
                              void* d_out, int out_size, void* d_ws, size_t ws_size,
                              hipStream_t stream) {
    const float* x     = (const float*)d_in[0];
    // d_in[1] = W1, d_in[2] = W2 : mathematically unused (softmax over size-1 axis)
    const float* W3    = (const float*)d_in[3];
    const float* W4    = (const float*)d_in[4];
    const float* gamma = (const float*)d_in[5];
    float* out = (float*)d_out;

    attn_collapsed_kernel<<<NBLOCKS, NTHREADS, 0, stream>>>(x, W3, W4, gamma, out);
}

// Round 3
// 284.375 us; speedup vs baseline: 2.5613x; 1.1412x over previous
//
#include <hip/hip_runtime.h>

// Reference collapses (softmax over size-1 axis == 1; reshapes are identity):
//   out = relu(x @ (gamma*W3 + W4)^T),  x:(B,20), fused M:(200,20)
// Memory floor: 210 MB out write + 21 MB x read => ~37 us @ 6.3 TB/s.
//
// R2 lesson: re-loading the x row per 8 B of output made each loop iter a
// serialized global-latency chain (1.5 TB/s, all pipes idle). Now:
//   - fused M staged in LDS once per block (broadcast reads, conflict-free)
//   - x loaded ONCE per thread (thread = one row-half), held in 20 regs
//   - inner loop: 25 independent LDS->FMA->float4-store groups, no global
//     loads, stores fire-and-forget.

#define BATCH          262144
#define DICT           20
#define COLS           200            // NUM_HEADS * DICT
#define NTHREADS       256
#define ROWS_PER_BLOCK 128            // threads 0-127: cols 0-99; 128-255: cols 100-199
#define NBLOCKS        (BATCH / ROWS_PER_BLOCK)   // 2048 blocks -> 8192 waves = all slots

__global__ __launch_bounds__(NTHREADS)
void attn_collapsed_kernel(const float* __restrict__ x,
                           const float* __restrict__ W3,
                           const float* __restrict__ W4,
                           const float* __restrict__ gamma,
                           float* __restrict__ out)
{
    // Fused weight matrix M[j][k] = g*W3[j][k] + W4[j][k], 200x20 fp32 = 16 KB.
    // Stored as 5 float4 per column j. All inner-loop reads are wave-uniform
    // addresses -> LDS broadcast, zero bank conflicts.
    __shared__ float4 ldsM[COLS * 5];

    const int t = threadIdx.x;
    const float g = gamma[0];

    const float4* w3 = (const float4*)W3;
    const float4* w4 = (const float4*)W4;
    for (int i = t; i < COLS * 5; i += NTHREADS) {   // 1000 float4, 4 iters
        float4 a = w3[i], b = w4[i], m;
        m.x = fmaf(g, a.x, b.x);
        m.y = fmaf(g, a.y, b.y);
        m.z = fmaf(g, a.z, b.z);
        m.w = fmaf(g, a.w, b.w);
        ldsM[i] = m;
    }
    __syncthreads();

    // Thread -> (row, column half). Waves 0,1: half 0; waves 2,3: half 1,
    // so the half (and every LDS address) is uniform within each wave.
    const int row     = blockIdx.x * ROWS_PER_BLOCK + (t & 127);
    const int colbase = (t >> 7) * 100;

    // x row: loaded once, lives in 20 VGPRs for all 25 output groups.
    float4 xv[5];
    {
        const float4* xr = (const float4*)(x + row * DICT);
#pragma unroll
        for (int i = 0; i < 5; ++i) xv[i] = xr[i];
    }

    float4* op = (float4*)(out + row * COLS + colbase);

#pragma unroll 5
    for (int c = 0; c < 25; ++c) {
        const float4* wp = &ldsM[(colbase + 4 * c) * 5];
        float4 acc;
        float* accp = (float*)&acc;
#pragma unroll
        for (int cc = 0; cc < 4; ++cc) {
            // dot(M[col+cc][:], x[:]) with two partial chains for ILP
            float p0 = 0.f, p1 = 0.f;
#pragma unroll
            for (int kk = 0; kk < 5; ++kk) {
                float4 w = wp[cc * 5 + kk];          // wave-uniform -> broadcast
                p0 = fmaf(w.x, xv[kk].x, p0);
                p1 = fmaf(w.y, xv[kk].y, p1);
                p0 = fmaf(w.z, xv[kk].z, p0);
                p1 = fmaf(w.w, xv[kk].w, p1);
            }
            accp[cc] = fmaxf(p0 + p1, 0.f);          // ReLU
        }
        op[c] = acc;   // independent 16 B stores, fire-and-forget
    }
}

extern "C" void kernel_launch(void* const* d_in, const int* in_sizes, int n_in,
                              void* d_out, int out_size, void* d_ws, size_t ws_size,
                              hipStream_t stream) {
    const float* x     = (const float*)d_in[0];
    // d_in[1] = W1, d_in[2] = W2 : mathematically unused (softmax over size-1 axis)
    const float* W3    = (const float*)d_in[3];
    const float* W4    = (const float*)d_in[4];
    const float* gamma = (const float*)d_in[5];
    float* out = (float*)d_out;

    attn_collapsed_kernel<<<NBLOCKS, NTHREADS, 0, stream>>>(x, W3, W4, gamma, out);
}